// Round 5
// baseline (341.142 us; speedup 1.0000x reference)
//
#include <hip/hip_runtime.h>

#define NN 50000
#define EE 600000
#define DD 128
#define CAP 64
#define CNTSTRIDE 16     // one 32b counter per 64B line: kills line-level atomic serialization
#define LDS_STRIDE 136   // shorts; conflict-free b128 LDS reads (SQ_LDS_BANK_CONFLICT=0 measured)

typedef __attribute__((ext_vector_type(8))) short bf16x8;
typedef __attribute__((ext_vector_type(4))) float f32x4;

__device__ __forceinline__ unsigned short f2bf(float f) {
    union { float f; unsigned u; } v; v.f = f;
    unsigned r = v.u + 0x7FFF + ((v.u >> 16) & 1);
    return (unsigned short)(r >> 16);
}
__device__ __forceinline__ float bflo(unsigned x) { return __uint_as_float(x << 16); }
__device__ __forceinline__ float bfhi(unsigned x) { return __uint_as_float(x & 0xffff0000u); }

// ---------------- CSR-bucket build ----------------
__global__ void fill_kernel(const int* __restrict__ src, const int* __restrict__ dst,
                            const float* __restrict__ ea,
                            int* __restrict__ cnt, int2* __restrict__ slots) {
    int e = blockIdx.x * 256 + threadIdx.x;
    if (e >= EE) return;
    int d = dst[e];
    int p = atomicAdd(&cnt[d * CNTSTRIDE], 1);
    if (p < CAP) {
        int2 v;
        v.x = src[e];
        v.y = __float_as_int(ea[e]);
        slots[d * CAP + p] = v;
    }
}

// ---------------- prep: node->bf16 convert + Wc=W@W1 + bc=b_rel@W1+b1 ----------------
__global__ void prep_kernel(const float* __restrict__ nodef, unsigned short* __restrict__ node_bf,
                            const float* __restrict__ W_rel, const float* __restrict__ W_root,
                            const float* __restrict__ W1, float* __restrict__ Wc,
                            const float* __restrict__ b_rel, const float* __restrict__ b1,
                            float* __restrict__ bc) {
    int b = blockIdx.x;
    if (b < 6250) {                       // convert: 6250*256 float4 = NN*DD
        int i = b * 256 + threadIdx.x;
        float4 v = *(const float4*)&nodef[(size_t)i * 4];
        ushort4 o;
        o.x = f2bf(v.x); o.y = f2bf(v.y); o.z = f2bf(v.z); o.w = f2bf(v.w);
        *(ushort4*)&node_bf[(size_t)i * 4] = o;
    } else if (b < 6250 + 96) {           // Wc: 6 products x 16 parts
        int bb = b - 6250;
        int which = bb >> 4, part = bb & 15;
        int l = (which < 3) ? which : which - 3;
        const float* A = (which < 3) ? (W_rel + (size_t)l * 16384) : (W_root + (size_t)l * 16384);
        const float* B = W1 + (size_t)l * 16384;
        float* out = Wc + (size_t)which * 16384;
        int o = part * 1024 + threadIdx.x;
        for (int rep = 0; rep < 4; ++rep, o += 256) {
            int i = o >> 7, j = o & 127;
            float s = 0.f;
            for (int k = 0; k < 128; ++k) s = fmaf(A[i * 128 + k], B[k * 128 + j], s);
            out[o] = s;
        }
    } else {                              // bc: 3 blocks
        int l = b - 6250 - 96;
        int j = threadIdx.x;
        if (j < 128) {
            float s = 0.f;
            for (int k = 0; k < 128; ++k)
                s = fmaf(b_rel[l * 128 + k], W1[(size_t)l * 16384 + k * 128 + j], s);
            bc[l * 128 + j] = s + b1[l * 128 + j];
        }
    }
}

// ---------------- pack weights into B-fragment-major bf16 ----------------
// 12 chunks: 0-2 Wc_rel[l], 3-5 Wc_root[l], 6-8 W2[l], 9-11 jk_W chunk l
__global__ void pack_w_kernel(const float* __restrict__ Wc, const float* __restrict__ W2,
                              const float* __restrict__ jkW, unsigned short* __restrict__ packed) {
    int t = blockIdx.x * 256 + threadIdx.x;   // 12*2048 threads
    int chunk = t >> 11;
    int r = t & 2047;
    int lane = r & 63;
    int tile = r >> 6;
    int kt = tile >> 3, nt = tile & 7;
    int quad = lane >> 4, n = lane & 15;
    const float* src;
    if (chunk < 6)       src = Wc  + (size_t)chunk * 16384;
    else if (chunk < 9)  src = W2  + (size_t)(chunk - 6) * 16384;
    else                 src = jkW + (size_t)(chunk - 9) * 16384;
    int k0 = kt * 32 + quad * 8;
    int col = nt * 16 + n;
    union { unsigned short u[8]; uint4 v; } tmp;
#pragma unroll
    for (int j = 0; j < 8; ++j) tmp.u[j] = f2bf(src[(size_t)(k0 + j) * DD + col]);
    *(uint4*)&packed[(size_t)t * 8] = tmp.v;
}

// ---------------- gather + mean: edge-group parallel, 16B/lane ----------------
// Wave = 1 node. 4 groups of 16 lanes; group g covers edge j+g; lane covers 8 bf16 cols.
__global__ __launch_bounds__(256) void gather_mean_kernel(
    const unsigned short* __restrict__ feat,
    const int2* __restrict__ slots,
    const int* __restrict__ cnt,
    unsigned short* __restrict__ mean) {
    const int node = (int)((blockIdx.x * 256 + threadIdx.x) >> 6);
    if (node >= NN) return;
    const int lane = threadIdx.x & 63;
    const int g  = lane >> 4;         // edge group 0..3
    const int h8 = (lane & 15) * 8;   // first bf16 column handled by this lane
    int c = cnt[node * CNTSTRIDE];
    if (c > CAP) c = CAP;
    const int2* sp = slots + (size_t)node * CAP;

    float acc[8] = {0.f, 0.f, 0.f, 0.f, 0.f, 0.f, 0.f, 0.f};

#define GSTEP(J) {                                                        \
        int idx = (J) + g;                                                \
        int cl  = idx < c ? idx : c - 1;                                  \
        int2 ev = sp[cl];                                                 \
        float w = idx < c ? __int_as_float(ev.y) : 0.0f;                  \
        uint4 v = *(const uint4*)&feat[(size_t)ev.x * DD + h8];           \
        acc[0] = fmaf(bflo(v.x), w, acc[0]);                              \
        acc[1] = fmaf(bfhi(v.x), w, acc[1]);                              \
        acc[2] = fmaf(bflo(v.y), w, acc[2]);                              \
        acc[3] = fmaf(bfhi(v.y), w, acc[3]);                              \
        acc[4] = fmaf(bflo(v.z), w, acc[4]);                              \
        acc[5] = fmaf(bfhi(v.z), w, acc[5]);                              \
        acc[6] = fmaf(bflo(v.w), w, acc[6]);                              \
        acc[7] = fmaf(bfhi(v.w), w, acc[7]);                              \
    }

    int j = 0;
    for (; j + 16 <= c; j += 16) {    // c can reach CAP=64
        GSTEP(j); GSTEP(j + 4); GSTEP(j + 8); GSTEP(j + 12);
    }
    if (j < c) {                      // predicated tail; branches are wave-uniform
        GSTEP(j);
        if (j + 4 < c)  GSTEP(j + 4);
        if (j + 8 < c)  GSTEP(j + 8);
        if (j + 12 < c) GSTEP(j + 12);
    }
#undef GSTEP

    // reduce across the 4 edge-groups (lanes l, l^16, l^32, l^48 share columns)
#pragma unroll
    for (int k = 0; k < 8; ++k) {
        acc[k] += __shfl_xor(acc[k], 16);
        acc[k] += __shfl_xor(acc[k], 32);
    }

    if (g == 0) {
        float id = 1.0f / fmaxf((float)c, 1.0f);
        union { unsigned short u[8]; uint4 v; } o;
#pragma unroll
        for (int k = 0; k < 8; ++k) o.u[k] = f2bf(acc[k] * id);
        *(uint4*)&mean[(size_t)node * DD + h8] = o.v;
    }
}

// ---------------- fused layer: LN1ReLU(mean@Wc_rel + node@Wc_root + bc) @ W2 + b2 -> LN2ReLU ----------------
// JK variant additionally computes d_out += out3@PJ2 + o0@PJ0 + o1@PJ1 + jkb and skips the bf16 out store.
template <bool JK>
__global__ __launch_bounds__(256) void fused_layer(
    const unsigned short* __restrict__ mean, const unsigned short* __restrict__ nodef,
    const unsigned short* __restrict__ PWrel, const unsigned short* __restrict__ PWroot,
    const unsigned short* __restrict__ PW2,
    const float* __restrict__ bc, const float* __restrict__ ln1g, const float* __restrict__ ln1b,
    const float* __restrict__ b2, const float* __restrict__ ln2g, const float* __restrict__ ln2b,
    unsigned short* __restrict__ out,
    const unsigned short* __restrict__ o0, const unsigned short* __restrict__ o1,
    const unsigned short* __restrict__ PJ0, const unsigned short* __restrict__ PJ1,
    const unsigned short* __restrict__ PJ2,
    const float* __restrict__ jkb, float* __restrict__ fout) {
    __shared__ unsigned short ldsA[2][64 * LDS_STRIDE];
    const int tid  = threadIdx.x;
    const int lane = tid & 63;
    const int wid  = tid >> 6;
    const int row0 = blockIdx.x * 64;

    const unsigned short* As[2] = {mean, nodef};
#pragma unroll
    for (int a = 0; a < 2; ++a) {
#pragma unroll
        for (int i = 0; i < 4; ++i) {
            int c = i * 256 + tid;
            int r = c >> 4, cc = (c & 15) * 8;
            if (row0 + r < NN)
                *(uint4*)&ldsA[a][r * LDS_STRIDE + cc] = *(const uint4*)&As[a][(size_t)(row0 + r) * DD + cc];
        }
    }
    __syncthreads();

    const int mrow  = row0 + wid * 16;
    const bool alive = mrow < NN;
    if (!JK && !alive) return;

    const int quad = lane >> 4, n15 = lane & 15;
    const int arow = wid * 16 + n15;
    const int kq   = quad * 8;

    f32x4 acc[8];
#pragma unroll
    for (int nt = 0; nt < 8; ++nt) acc[nt] = (f32x4){0.f, 0.f, 0.f, 0.f};
#pragma unroll
    for (int kt = 0; kt < 4; ++kt) {
        bf16x8 am = *(const bf16x8*)&ldsA[0][arow * LDS_STRIDE + kt * 32 + kq];
        bf16x8 an = *(const bf16x8*)&ldsA[1][arow * LDS_STRIDE + kt * 32 + kq];
#pragma unroll
        for (int nt = 0; nt < 8; ++nt) {
            bf16x8 brel = *(const bf16x8*)&PWrel[(size_t)((kt * 8 + nt) * 64 + lane) * 8];
            acc[nt] = __builtin_amdgcn_mfma_f32_16x16x32_bf16(am, brel, acc[nt], 0, 0, 0);
            bf16x8 brt = *(const bf16x8*)&PWroot[(size_t)((kt * 8 + nt) * 64 + lane) * 8];
            acc[nt] = __builtin_amdgcn_mfma_f32_16x16x32_bf16(an, brt, acc[nt], 0, 0, 0);
        }
    }

    float x[8][4];
#pragma unroll
    for (int nt = 0; nt < 8; ++nt) {
        float bv = bc[nt * 16 + n15];
#pragma unroll
        for (int r = 0; r < 4; ++r) x[nt][r] = acc[nt][r] + bv;
    }
    {   // LN1 + ReLU
        float s[4] = {0, 0, 0, 0}, q[4] = {0, 0, 0, 0};
#pragma unroll
        for (int nt = 0; nt < 8; ++nt)
#pragma unroll
            for (int r = 0; r < 4; ++r) { s[r] += x[nt][r]; q[r] += x[nt][r] * x[nt][r]; }
#pragma unroll
        for (int m = 1; m <= 8; m <<= 1)
#pragma unroll
            for (int r = 0; r < 4; ++r) { s[r] += __shfl_xor(s[r], m); q[r] += __shfl_xor(q[r], m); }
        const float inv = 1.0f / 128.0f;
#pragma unroll
        for (int r = 0; r < 4; ++r) {
            float mu = s[r] * inv;
            float rs = rsqrtf(fmaxf(q[r] * inv - mu * mu, 0.0f) + 1e-5f);
#pragma unroll
            for (int nt = 0; nt < 8; ++nt) {
                float g = ln1g[nt * 16 + n15], bb = ln1b[nt * 16 + n15];
                x[nt][r] = fmaxf((x[nt][r] - mu) * rs * g + bb, 0.0f);
            }
        }
    }

    // relayout C->A via wave-private LDS rows (aliases this wave's 16 rows of tile 0)
    unsigned short* wt = &ldsA[0][wid * 16 * LDS_STRIDE];
#pragma unroll
    for (int nt = 0; nt < 8; ++nt)
#pragma unroll
        for (int r = 0; r < 4; ++r)
            wt[(quad * 4 + r) * LDS_STRIDE + nt * 16 + n15] = f2bf(x[nt][r]);
    __asm__ __volatile__("s_waitcnt lgkmcnt(0)" ::: "memory");

    f32x4 acc2[8];
#pragma unroll
    for (int nt = 0; nt < 8; ++nt) acc2[nt] = (f32x4){0.f, 0.f, 0.f, 0.f};
#pragma unroll
    for (int kt = 0; kt < 4; ++kt) {
        bf16x8 ah = *(const bf16x8*)&wt[n15 * LDS_STRIDE + kt * 32 + kq];
#pragma unroll
        for (int nt = 0; nt < 8; ++nt) {
            bf16x8 bw = *(const bf16x8*)&PW2[(size_t)((kt * 8 + nt) * 64 + lane) * 8];
            acc2[nt] = __builtin_amdgcn_mfma_f32_16x16x32_bf16(ah, bw, acc2[nt], 0, 0, 0);
        }
    }
#pragma unroll
    for (int nt = 0; nt < 8; ++nt) {
        float bv = b2[nt * 16 + n15];
#pragma unroll
        for (int r = 0; r < 4; ++r) x[nt][r] = acc2[nt][r] + bv;
    }
    {   // LN2 + ReLU
        float s[4] = {0, 0, 0, 0}, q[4] = {0, 0, 0, 0};
#pragma unroll
        for (int nt = 0; nt < 8; ++nt)
#pragma unroll
            for (int r = 0; r < 4; ++r) { s[r] += x[nt][r]; q[r] += x[nt][r] * x[nt][r]; }
#pragma unroll
        for (int m = 1; m <= 8; m <<= 1)
#pragma unroll
            for (int r = 0; r < 4; ++r) { s[r] += __shfl_xor(s[r], m); q[r] += __shfl_xor(q[r], m); }
        const float inv = 1.0f / 128.0f;
#pragma unroll
        for (int r = 0; r < 4; ++r) {
            float mu = s[r] * inv;
            float rs = rsqrtf(fmaxf(q[r] * inv - mu * mu, 0.0f) + 1e-5f);
#pragma unroll
            for (int nt = 0; nt < 8; ++nt) {
                float g = ln2g[nt * 16 + n15], bb = ln2b[nt * 16 + n15];
                x[nt][r] = fmaxf((x[nt][r] - mu) * rs * g + bb, 0.0f);
            }
        }
    }

    if constexpr (!JK) {
        // bounce through LDS for coalesced 16B stores
        __asm__ __volatile__("s_waitcnt lgkmcnt(0)" ::: "memory");
#pragma unroll
        for (int nt = 0; nt < 8; ++nt)
#pragma unroll
            for (int r = 0; r < 4; ++r)
                wt[(quad * 4 + r) * LDS_STRIDE + nt * 16 + n15] = f2bf(x[nt][r]);
        __asm__ __volatile__("s_waitcnt lgkmcnt(0)" ::: "memory");
#pragma unroll
        for (int i = 0; i < 4; ++i) {
            int s = i * 512 + lane * 8;
            int r = s >> 7, col = s & 127;
            uint4 v = *(const uint4*)&wt[r * LDS_STRIDE + col];
            *(uint4*)&out[(size_t)(mrow + r) * DD + col] = v;
        }
    } else {
        // write out3 (bf16-rounded) into wave-private tile as stage-3 A operand
        __asm__ __volatile__("s_waitcnt lgkmcnt(0)" ::: "memory");
#pragma unroll
        for (int nt = 0; nt < 8; ++nt)
#pragma unroll
            for (int r = 0; r < 4; ++r)
                wt[(quad * 4 + r) * LDS_STRIDE + nt * 16 + n15] = f2bf(x[nt][r]);
        __asm__ __volatile__("s_waitcnt lgkmcnt(0)" ::: "memory");

        f32x4 accJ[8];
#pragma unroll
        for (int nt = 0; nt < 8; ++nt) accJ[nt] = (f32x4){0.f, 0.f, 0.f, 0.f};
#pragma unroll
        for (int kt = 0; kt < 4; ++kt) {
            bf16x8 ah = *(const bf16x8*)&wt[n15 * LDS_STRIDE + kt * 32 + kq];
#pragma unroll
            for (int nt = 0; nt < 8; ++nt) {
                bf16x8 bw = *(const bf16x8*)&PJ2[(size_t)((kt * 8 + nt) * 64 + lane) * 8];
                accJ[nt] = __builtin_amdgcn_mfma_f32_16x16x32_bf16(ah, bw, accJ[nt], 0, 0, 0);
            }
        }
        // cycle ldsA[1] through o0 then o1
        const unsigned short* oo[2] = {o0, o1};
        const unsigned short* PJs[2] = {PJ0, PJ1};
#pragma unroll
        for (int a = 0; a < 2; ++a) {
            __syncthreads();
#pragma unroll
            for (int i = 0; i < 4; ++i) {
                int c = i * 256 + tid;
                int r = c >> 4, cc = (c & 15) * 8;
                if (row0 + r < NN)
                    *(uint4*)&ldsA[1][r * LDS_STRIDE + cc] = *(const uint4*)&oo[a][(size_t)(row0 + r) * DD + cc];
            }
            __syncthreads();
#pragma unroll
            for (int kt = 0; kt < 4; ++kt) {
                bf16x8 ah = *(const bf16x8*)&ldsA[1][arow * LDS_STRIDE + kt * 32 + kq];
#pragma unroll
                for (int nt = 0; nt < 8; ++nt) {
                    bf16x8 bw = *(const bf16x8*)&PJs[a][(size_t)((kt * 8 + nt) * 64 + lane) * 8];
                    accJ[nt] = __builtin_amdgcn_mfma_f32_16x16x32_bf16(ah, bw, accJ[nt], 0, 0, 0);
                }
            }
        }
        if (alive) {
#pragma unroll
            for (int nt = 0; nt < 8; ++nt) {
                float bv = jkb[nt * 16 + n15];
#pragma unroll
                for (int r = 0; r < 4; ++r)
                    fout[(size_t)(mrow + quad * 4 + r) * DD + nt * 16 + n15] = accJ[nt][r] + bv;
            }
        }
    }
}

// ---------------- launcher ----------------
extern "C" void kernel_launch(void* const* d_in, const int* in_sizes, int n_in,
                              void* d_out, int out_size, void* d_ws, size_t ws_size,
                              hipStream_t stream) {
    const float* node   = (const float*)d_in[0];
    const float* ea     = (const float*)d_in[1];
    const float* W_rel  = (const float*)d_in[2];
    const float* b_rel  = (const float*)d_in[3];
    const float* W_root = (const float*)d_in[4];
    const float* ln1_g  = (const float*)d_in[5];
    const float* ln1_b  = (const float*)d_in[6];
    const float* ln2_g  = (const float*)d_in[7];
    const float* ln2_b  = (const float*)d_in[8];
    const float* W1     = (const float*)d_in[9];
    const float* b1     = (const float*)d_in[10];
    const float* W2     = (const float*)d_in[11];
    const float* b2     = (const float*)d_in[12];
    const float* jk_W   = (const float*)d_in[13];
    const float* jk_b   = (const float*)d_in[14];
    const int*   ei     = (const int*)d_in[15];
    const int* srcI = ei;
    const int* dstI = ei + EE;

    char* ws = (char*)d_ws;
    size_t off = 0;
    auto alloc = [&](size_t bytes) {
        void* p = ws + off;
        off += (bytes + 255) & ~(size_t)255;
        return p;
    };
    int*            cnt     = (int*)alloc((size_t)NN * CNTSTRIDE * 4);
    int2*           slots   = (int2*)alloc((size_t)NN * CAP * 8);
    unsigned short* node_bf = (unsigned short*)alloc((size_t)NN * DD * 2);
    unsigned short* mean_bf = (unsigned short*)alloc((size_t)NN * DD * 2);
    unsigned short* outs_bf[2];
    for (int l = 0; l < 2; ++l) outs_bf[l] = (unsigned short*)alloc((size_t)NN * DD * 2);
    float*          Wc      = (float*)alloc((size_t)6 * 16384 * 4);
    float*          bc      = (float*)alloc((size_t)3 * 128 * 4);
    unsigned short* packed  = (unsigned short*)alloc((size_t)12 * 16384 * 2);

    hipMemsetAsync(cnt, 0, (size_t)NN * CNTSTRIDE * 4, stream);
    prep_kernel<<<6250 + 96 + 3, 256, 0, stream>>>(node, node_bf, W_rel, W_root, W1, Wc, b_rel, b1, bc);
    fill_kernel<<<(EE + 255) / 256, 256, 0, stream>>>(srcI, dstI, ea, cnt, slots);
    pack_w_kernel<<<12 * 2048 / 256, 256, 0, stream>>>(Wc, W2, jk_W, packed);

    const int gblocks = (NN + 63) / 64;   // 782
    unsigned short* cur = node_bf;
    for (int l = 0; l < 3; ++l) {
        gather_mean_kernel<<<NN / 4, 256, 0, stream>>>(cur, slots, cnt, mean_bf);
        if (l < 2) {
            fused_layer<false><<<gblocks, 256, 0, stream>>>(
                mean_bf, cur,
                packed + (size_t)l * 16384, packed + (size_t)(3 + l) * 16384,
                packed + (size_t)(6 + l) * 16384,
                bc + (size_t)l * DD, ln1_g + (size_t)l * DD, ln1_b + (size_t)l * DD,
                b2 + (size_t)l * DD, ln2_g + (size_t)l * DD, ln2_b + (size_t)l * DD,
                outs_bf[l],
                nullptr, nullptr, nullptr, nullptr, nullptr, nullptr, nullptr);
            cur = outs_bf[l];
        } else {
            fused_layer<true><<<gblocks, 256, 0, stream>>>(
                mean_bf, cur,
                packed + (size_t)l * 16384, packed + (size_t)(3 + l) * 16384,
                packed + (size_t)(6 + l) * 16384,
                bc + (size_t)l * DD, ln1_g + (size_t)l * DD, ln1_b + (size_t)l * DD,
                b2 + (size_t)l * DD, ln2_g + (size_t)l * DD, ln2_b + (size_t)l * DD,
                nullptr,
                outs_bf[0], outs_bf[1],
                packed + (size_t)9 * 16384, packed + (size_t)10 * 16384, packed + (size_t)11 * 16384,
                jk_b, (float*)d_out);
        }
    }
}

// Round 6
// 328.585 us; speedup vs baseline: 1.0382x; 1.0382x over previous
//
#include <hip/hip_runtime.h>

#define NN 50000
#define EE 600000
#define DD 128
#define CAP 64
#define CNTSTRIDE 16     // one 32b counter per 64B line: kills line-level atomic serialization
#define LDS_STRIDE 136   // shorts; conflict-free b128 LDS reads

typedef __attribute__((ext_vector_type(8))) short bf16x8;
typedef __attribute__((ext_vector_type(4))) float f32x4;

__device__ __forceinline__ unsigned short f2bf(float f) {
    union { float f; unsigned u; } v; v.f = f;
    unsigned r = v.u + 0x7FFF + ((v.u >> 16) & 1);
    return (unsigned short)(r >> 16);
}
__device__ __forceinline__ float bflo(unsigned x) { return __uint_as_float(x << 16); }
__device__ __forceinline__ float bfhi(unsigned x) { return __uint_as_float(x & 0xffff0000u); }

// ---------------- CSR-bucket build ----------------
__global__ void fill_kernel(const int* __restrict__ src, const int* __restrict__ dst,
                            const float* __restrict__ ea,
                            int* __restrict__ cnt, int2* __restrict__ slots) {
    int e = blockIdx.x * 256 + threadIdx.x;
    if (e >= EE) return;
    int d = dst[e];
    int p = atomicAdd(&cnt[d * CNTSTRIDE], 1);
    if (p < CAP) {
        int2 v;
        v.x = src[e];
        v.y = __float_as_int(ea[e]);
        slots[d * CAP + p] = v;
    }
}

// ---------------- prep: node->bf16 convert + Wc=W@W1 + bc=b_rel@W1+b1 ----------------
__global__ void prep_kernel(const float* __restrict__ nodef, unsigned short* __restrict__ node_bf,
                            const float* __restrict__ W_rel, const float* __restrict__ W_root,
                            const float* __restrict__ W1, float* __restrict__ Wc,
                            const float* __restrict__ b_rel, const float* __restrict__ b1,
                            float* __restrict__ bc) {
    int b = blockIdx.x;
    if (b < 6250) {                       // convert: 6250*256 float4 = NN*DD
        int i = b * 256 + threadIdx.x;
        float4 v = *(const float4*)&nodef[(size_t)i * 4];
        ushort4 o;
        o.x = f2bf(v.x); o.y = f2bf(v.y); o.z = f2bf(v.z); o.w = f2bf(v.w);
        *(ushort4*)&node_bf[(size_t)i * 4] = o;
    } else if (b < 6250 + 96) {           // Wc: 6 products x 16 parts
        int bb = b - 6250;
        int which = bb >> 4, part = bb & 15;
        int l = (which < 3) ? which : which - 3;
        const float* A = (which < 3) ? (W_rel + (size_t)l * 16384) : (W_root + (size_t)l * 16384);
        const float* B = W1 + (size_t)l * 16384;
        float* out = Wc + (size_t)which * 16384;
        int o = part * 1024 + threadIdx.x;
        for (int rep = 0; rep < 4; ++rep, o += 256) {
            int i = o >> 7, j = o & 127;
            float s = 0.f;
            for (int k = 0; k < 128; ++k) s = fmaf(A[i * 128 + k], B[k * 128 + j], s);
            out[o] = s;
        }
    } else {                              // bc: 3 blocks
        int l = b - 6250 - 96;
        int j = threadIdx.x;
        if (j < 128) {
            float s = 0.f;
            for (int k = 0; k < 128; ++k)
                s = fmaf(b_rel[l * 128 + k], W1[(size_t)l * 16384 + k * 128 + j], s);
            bc[l * 128 + j] = s + b1[l * 128 + j];
        }
    }
}

// ---------------- pack weights into B-fragment-major bf16 ----------------
// 12 chunks: 0-2 Wc_rel[l], 3-5 Wc_root[l], 6-8 W2[l], 9-11 jk_W chunk l
__global__ void pack_w_kernel(const float* __restrict__ Wc, const float* __restrict__ W2,
                              const float* __restrict__ jkW, unsigned short* __restrict__ packed) {
    int t = blockIdx.x * 256 + threadIdx.x;   // 12*2048 threads
    int chunk = t >> 11;
    int r = t & 2047;
    int lane = r & 63;
    int tile = r >> 6;
    int kt = tile >> 3, nt = tile & 7;
    int quad = lane >> 4, n = lane & 15;
    const float* src;
    if (chunk < 6)       src = Wc  + (size_t)chunk * 16384;
    else if (chunk < 9)  src = W2  + (size_t)(chunk - 6) * 16384;
    else                 src = jkW + (size_t)(chunk - 9) * 16384;
    int k0 = kt * 32 + quad * 8;
    int col = nt * 16 + n;
    union { unsigned short u[8]; uint4 v; } tmp;
#pragma unroll
    for (int j = 0; j < 8; ++j) tmp.u[j] = f2bf(src[(size_t)(k0 + j) * DD + col]);
    *(uint4*)&packed[(size_t)t * 8] = tmp.v;
}

// ---------------- gather + mean: edge-group parallel, 16B/lane ----------------
__global__ __launch_bounds__(256) void gather_mean_kernel(
    const unsigned short* __restrict__ feat,
    const int2* __restrict__ slots,
    const int* __restrict__ cnt,
    unsigned short* __restrict__ mean) {
    const int node = (int)((blockIdx.x * 256 + threadIdx.x) >> 6);
    if (node >= NN) return;
    const int lane = threadIdx.x & 63;
    const int g  = lane >> 4;         // edge group 0..3
    const int h8 = (lane & 15) * 8;   // first bf16 column handled by this lane
    int c = cnt[node * CNTSTRIDE];
    if (c > CAP) c = CAP;
    const int2* sp = slots + (size_t)node * CAP;

    float acc[8] = {0.f, 0.f, 0.f, 0.f, 0.f, 0.f, 0.f, 0.f};

#define GSTEP(J) {                                                        \
        int idx = (J) + g;                                                \
        int cl  = idx < c ? idx : c - 1;                                  \
        int2 ev = sp[cl];                                                 \
        float w = idx < c ? __int_as_float(ev.y) : 0.0f;                  \
        uint4 v = *(const uint4*)&feat[(size_t)ev.x * DD + h8];           \
        acc[0] = fmaf(bflo(v.x), w, acc[0]);                              \
        acc[1] = fmaf(bfhi(v.x), w, acc[1]);                              \
        acc[2] = fmaf(bflo(v.y), w, acc[2]);                              \
        acc[3] = fmaf(bfhi(v.y), w, acc[3]);                              \
        acc[4] = fmaf(bflo(v.z), w, acc[4]);                              \
        acc[5] = fmaf(bfhi(v.z), w, acc[5]);                              \
        acc[6] = fmaf(bflo(v.w), w, acc[6]);                              \
        acc[7] = fmaf(bfhi(v.w), w, acc[7]);                              \
    }

    int j = 0;
    for (; j + 16 <= c; j += 16) {
        GSTEP(j); GSTEP(j + 4); GSTEP(j + 8); GSTEP(j + 12);
    }
    if (j < c) {
        GSTEP(j);
        if (j + 4 < c)  GSTEP(j + 4);
        if (j + 8 < c)  GSTEP(j + 8);
        if (j + 12 < c) GSTEP(j + 12);
    }
#undef GSTEP

#pragma unroll
    for (int k = 0; k < 8; ++k) {
        acc[k] += __shfl_xor(acc[k], 16);
        acc[k] += __shfl_xor(acc[k], 32);
    }

    if (g == 0) {
        float id = 1.0f / fmaxf((float)c, 1.0f);
        union { unsigned short u[8]; uint4 v; } o;
#pragma unroll
        for (int k = 0; k < 8; ++k) o.u[k] = f2bf(acc[k] * id);
        *(uint4*)&mean[(size_t)node * DD + h8] = o.v;
    }
}

// ---------------- barrier-free fused layer ----------------
// LN1ReLU(mean@Wc_rel + node@Wc_root + bc) @ W2 + b2 -> LN2ReLU [-> JK accumulate -> fp32 d_out]
// Wave = 16 rows, fully independent. A-fragments loaded directly from global
// (one wave-load = 16 full 64B lines). LDS: wave-private relayout tile only.
template <bool JK>
__global__ __launch_bounds__(256) void fused_layer(
    const unsigned short* __restrict__ mean, const unsigned short* __restrict__ nodef,
    const unsigned short* __restrict__ PWrel, const unsigned short* __restrict__ PWroot,
    const unsigned short* __restrict__ PW2,
    const float* __restrict__ bc, const float* __restrict__ ln1g, const float* __restrict__ ln1b,
    const float* __restrict__ b2, const float* __restrict__ ln2g, const float* __restrict__ ln2b,
    unsigned short* __restrict__ out,
    const unsigned short* __restrict__ o0, const unsigned short* __restrict__ o1,
    const unsigned short* __restrict__ PJ0, const unsigned short* __restrict__ PJ1,
    const unsigned short* __restrict__ PJ2,
    const float* __restrict__ jkb, float* __restrict__ fout) {
    __shared__ unsigned short relay[4][16 * LDS_STRIDE];   // one tile per wave
    const int lane = threadIdx.x & 63;
    const int wid  = threadIdx.x >> 6;
    const int mrow = blockIdx.x * 64 + wid * 16;
    if (mrow >= NN) return;                                // barrier-free: safe

    const int quad = lane >> 4, n15 = lane & 15;
    const int kq   = quad * 8;
    unsigned short* wt = relay[wid];

    const unsigned short* Am = mean  + (size_t)(mrow + n15) * DD;
    const unsigned short* An = nodef + (size_t)(mrow + n15) * DD;

    // ---- stage 1: mean@Wc_rel + node@Wc_root ----
    f32x4 acc[8];
#pragma unroll
    for (int nt = 0; nt < 8; ++nt) acc[nt] = (f32x4){0.f, 0.f, 0.f, 0.f};
#pragma unroll
    for (int kt = 0; kt < 4; ++kt) {
        bf16x8 am = *(const bf16x8*)&Am[kt * 32 + kq];
        bf16x8 an = *(const bf16x8*)&An[kt * 32 + kq];
#pragma unroll
        for (int nt = 0; nt < 8; ++nt) {
            bf16x8 brel = *(const bf16x8*)&PWrel[(size_t)((kt * 8 + nt) * 64 + lane) * 8];
            acc[nt] = __builtin_amdgcn_mfma_f32_16x16x32_bf16(am, brel, acc[nt], 0, 0, 0);
            bf16x8 brt = *(const bf16x8*)&PWroot[(size_t)((kt * 8 + nt) * 64 + lane) * 8];
            acc[nt] = __builtin_amdgcn_mfma_f32_16x16x32_bf16(an, brt, acc[nt], 0, 0, 0);
        }
    }

    float x[8][4];
#pragma unroll
    for (int nt = 0; nt < 8; ++nt) {
        float bv = bc[nt * 16 + n15];
#pragma unroll
        for (int r = 0; r < 4; ++r) x[nt][r] = acc[nt][r] + bv;
    }
    {   // LN1 + ReLU
        float s[4] = {0, 0, 0, 0}, q[4] = {0, 0, 0, 0};
#pragma unroll
        for (int nt = 0; nt < 8; ++nt)
#pragma unroll
            for (int r = 0; r < 4; ++r) { s[r] += x[nt][r]; q[r] += x[nt][r] * x[nt][r]; }
#pragma unroll
        for (int m = 1; m <= 8; m <<= 1)
#pragma unroll
            for (int r = 0; r < 4; ++r) { s[r] += __shfl_xor(s[r], m); q[r] += __shfl_xor(q[r], m); }
        const float inv = 1.0f / 128.0f;
#pragma unroll
        for (int r = 0; r < 4; ++r) {
            float mu = s[r] * inv;
            float rs = rsqrtf(fmaxf(q[r] * inv - mu * mu, 0.0f) + 1e-5f);
#pragma unroll
            for (int nt = 0; nt < 8; ++nt) {
                float g = ln1g[nt * 16 + n15], bb = ln1b[nt * 16 + n15];
                x[nt][r] = fmaxf((x[nt][r] - mu) * rs * g + bb, 0.0f);
            }
        }
    }

    // ---- relayout C->A via wave-private LDS tile ----
#pragma unroll
    for (int nt = 0; nt < 8; ++nt)
#pragma unroll
        for (int r = 0; r < 4; ++r)
            wt[(quad * 4 + r) * LDS_STRIDE + nt * 16 + n15] = f2bf(x[nt][r]);
    __asm__ __volatile__("s_waitcnt lgkmcnt(0)" ::: "memory");

    // ---- stage 2: @W2 ----
    f32x4 acc2[8];
#pragma unroll
    for (int nt = 0; nt < 8; ++nt) acc2[nt] = (f32x4){0.f, 0.f, 0.f, 0.f};
#pragma unroll
    for (int kt = 0; kt < 4; ++kt) {
        bf16x8 ah = *(const bf16x8*)&wt[n15 * LDS_STRIDE + kt * 32 + kq];
#pragma unroll
        for (int nt = 0; nt < 8; ++nt) {
            bf16x8 bw = *(const bf16x8*)&PW2[(size_t)((kt * 8 + nt) * 64 + lane) * 8];
            acc2[nt] = __builtin_amdgcn_mfma_f32_16x16x32_bf16(ah, bw, acc2[nt], 0, 0, 0);
        }
    }
#pragma unroll
    for (int nt = 0; nt < 8; ++nt) {
        float bv = b2[nt * 16 + n15];
#pragma unroll
        for (int r = 0; r < 4; ++r) x[nt][r] = acc2[nt][r] + bv;
    }
    {   // LN2 + ReLU
        float s[4] = {0, 0, 0, 0}, q[4] = {0, 0, 0, 0};
#pragma unroll
        for (int nt = 0; nt < 8; ++nt)
#pragma unroll
            for (int r = 0; r < 4; ++r) { s[r] += x[nt][r]; q[r] += x[nt][r] * x[nt][r]; }
#pragma unroll
        for (int m = 1; m <= 8; m <<= 1)
#pragma unroll
            for (int r = 0; r < 4; ++r) { s[r] += __shfl_xor(s[r], m); q[r] += __shfl_xor(q[r], m); }
        const float inv = 1.0f / 128.0f;
#pragma unroll
        for (int r = 0; r < 4; ++r) {
            float mu = s[r] * inv;
            float rs = rsqrtf(fmaxf(q[r] * inv - mu * mu, 0.0f) + 1e-5f);
#pragma unroll
            for (int nt = 0; nt < 8; ++nt) {
                float g = ln2g[nt * 16 + n15], bb = ln2b[nt * 16 + n15];
                x[nt][r] = fmaxf((x[nt][r] - mu) * rs * g + bb, 0.0f);
            }
        }
    }

    // ---- write out3 into wave tile (bf16-rounded; also A operand for JK) ----
    __asm__ __volatile__("s_waitcnt lgkmcnt(0)" ::: "memory");
#pragma unroll
    for (int nt = 0; nt < 8; ++nt)
#pragma unroll
        for (int r = 0; r < 4; ++r)
            wt[(quad * 4 + r) * LDS_STRIDE + nt * 16 + n15] = f2bf(x[nt][r]);
    __asm__ __volatile__("s_waitcnt lgkmcnt(0)" ::: "memory");

    if constexpr (!JK) {
        // coalesced 16B stores via the tile
#pragma unroll
        for (int i = 0; i < 4; ++i) {
            int s = i * 512 + lane * 8;
            int r = s >> 7, col = s & 127;
            uint4 v = *(const uint4*)&wt[r * LDS_STRIDE + col];
            *(uint4*)&out[(size_t)(mrow + r) * DD + col] = v;
        }
    } else {
        // JK: out3@PJ2 from the tile, o0@PJ0 + o1@PJ1 straight from global
        f32x4 accJ[8];
#pragma unroll
        for (int nt = 0; nt < 8; ++nt) accJ[nt] = (f32x4){0.f, 0.f, 0.f, 0.f};
#pragma unroll
        for (int kt = 0; kt < 4; ++kt) {
            bf16x8 ah = *(const bf16x8*)&wt[n15 * LDS_STRIDE + kt * 32 + kq];
#pragma unroll
            for (int nt = 0; nt < 8; ++nt) {
                bf16x8 bw = *(const bf16x8*)&PJ2[(size_t)((kt * 8 + nt) * 64 + lane) * 8];
                accJ[nt] = __builtin_amdgcn_mfma_f32_16x16x32_bf16(ah, bw, accJ[nt], 0, 0, 0);
            }
        }
        const unsigned short* A0 = o0 + (size_t)(mrow + n15) * DD;
        const unsigned short* A1 = o1 + (size_t)(mrow + n15) * DD;
#pragma unroll
        for (int kt = 0; kt < 4; ++kt) {
            bf16x8 a0 = *(const bf16x8*)&A0[kt * 32 + kq];
            bf16x8 a1 = *(const bf16x8*)&A1[kt * 32 + kq];
#pragma unroll
            for (int nt = 0; nt < 8; ++nt) {
                bf16x8 b0 = *(const bf16x8*)&PJ0[(size_t)((kt * 8 + nt) * 64 + lane) * 8];
                accJ[nt] = __builtin_amdgcn_mfma_f32_16x16x32_bf16(a0, b0, accJ[nt], 0, 0, 0);
                bf16x8 b1 = *(const bf16x8*)&PJ1[(size_t)((kt * 8 + nt) * 64 + lane) * 8];
                accJ[nt] = __builtin_amdgcn_mfma_f32_16x16x32_bf16(a1, b1, accJ[nt], 0, 0, 0);
            }
        }
#pragma unroll
        for (int nt = 0; nt < 8; ++nt) {
            float bv = jkb[nt * 16 + n15];
#pragma unroll
            for (int r = 0; r < 4; ++r)
                fout[(size_t)(mrow + quad * 4 + r) * DD + nt * 16 + n15] = accJ[nt][r] + bv;
        }
    }
}

// ---------------- launcher ----------------
extern "C" void kernel_launch(void* const* d_in, const int* in_sizes, int n_in,
                              void* d_out, int out_size, void* d_ws, size_t ws_size,
                              hipStream_t stream) {
    const float* node   = (const float*)d_in[0];
    const float* ea     = (const float*)d_in[1];
    const float* W_rel  = (const float*)d_in[2];
    const float* b_rel  = (const float*)d_in[3];
    const float* W_root = (const float*)d_in[4];
    const float* ln1_g  = (const float*)d_in[5];
    const float* ln1_b  = (const float*)d_in[6];
    const float* ln2_g  = (const float*)d_in[7];
    const float* ln2_b  = (const float*)d_in[8];
    const float* W1     = (const float*)d_in[9];
    const float* b1     = (const float*)d_in[10];
    const float* W2     = (const float*)d_in[11];
    const float* b2     = (const float*)d_in[12];
    const float* jk_W   = (const float*)d_in[13];
    const float* jk_b   = (const float*)d_in[14];
    const int*   ei     = (const int*)d_in[15];
    const int* srcI = ei;
    const int* dstI = ei + EE;

    char* ws = (char*)d_ws;
    size_t off = 0;
    auto alloc = [&](size_t bytes) {
        void* p = ws + off;
        off += (bytes + 255) & ~(size_t)255;
        return p;
    };
    int*            cnt     = (int*)alloc((size_t)NN * CNTSTRIDE * 4);
    int2*           slots   = (int2*)alloc((size_t)NN * CAP * 8);
    unsigned short* node_bf = (unsigned short*)alloc((size_t)NN * DD * 2);
    unsigned short* mean_bf = (unsigned short*)alloc((size_t)NN * DD * 2);
    unsigned short* outs_bf[2];
    for (int l = 0; l < 2; ++l) outs_bf[l] = (unsigned short*)alloc((size_t)NN * DD * 2);
    float*          Wc      = (float*)alloc((size_t)6 * 16384 * 4);
    float*          bc      = (float*)alloc((size_t)3 * 128 * 4);
    unsigned short* packed  = (unsigned short*)alloc((size_t)12 * 16384 * 2);

    hipMemsetAsync(cnt, 0, (size_t)NN * CNTSTRIDE * 4, stream);
    prep_kernel<<<6250 + 96 + 3, 256, 0, stream>>>(node, node_bf, W_rel, W_root, W1, Wc, b_rel, b1, bc);
    fill_kernel<<<(EE + 255) / 256, 256, 0, stream>>>(srcI, dstI, ea, cnt, slots);
    pack_w_kernel<<<12 * 2048 / 256, 256, 0, stream>>>(Wc, W2, jk_W, packed);

    const int gblocks = (NN + 63) / 64;   // 782
    unsigned short* cur = node_bf;
    for (int l = 0; l < 3; ++l) {
        gather_mean_kernel<<<NN / 4, 256, 0, stream>>>(cur, slots, cnt, mean_bf);
        if (l < 2) {
            fused_layer<false><<<gblocks, 256, 0, stream>>>(
                mean_bf, cur,
                packed + (size_t)l * 16384, packed + (size_t)(3 + l) * 16384,
                packed + (size_t)(6 + l) * 16384,
                bc + (size_t)l * DD, ln1_g + (size_t)l * DD, ln1_b + (size_t)l * DD,
                b2 + (size_t)l * DD, ln2_g + (size_t)l * DD, ln2_b + (size_t)l * DD,
                outs_bf[l],
                nullptr, nullptr, nullptr, nullptr, nullptr, nullptr, nullptr);
            cur = outs_bf[l];
        } else {
            fused_layer<true><<<gblocks, 256, 0, stream>>>(
                mean_bf, cur,
                packed + (size_t)l * 16384, packed + (size_t)(3 + l) * 16384,
                packed + (size_t)(6 + l) * 16384,
                bc + (size_t)l * DD, ln1_g + (size_t)l * DD, ln1_b + (size_t)l * DD,
                b2 + (size_t)l * DD, ln2_g + (size_t)l * DD, ln2_b + (size_t)l * DD,
                nullptr,
                outs_bf[0], outs_bf[1],
                packed + (size_t)9 * 16384, packed + (size_t)10 * 16384, packed + (size_t)11 * 16384,
                jk_b, (float*)d_out);
        }
    }
}

// Round 7
// 304.831 us; speedup vs baseline: 1.1191x; 1.0779x over previous
//
#include <hip/hip_runtime.h>

#define NN 50000
#define EE 600000
#define DD 128
#define CAP 64
#define CNTSTRIDE 16     // one 32b counter per 64B line: kills line-level atomic serialization
#define LDS_STRIDE 136   // shorts; conflict-free b128 LDS reads

typedef __attribute__((ext_vector_type(8))) short bf16x8;
typedef __attribute__((ext_vector_type(4))) float f32x4;

__device__ __forceinline__ unsigned short f2bf(float f) {
    union { float f; unsigned u; } v; v.f = f;
    unsigned r = v.u + 0x7FFF + ((v.u >> 16) & 1);
    return (unsigned short)(r >> 16);
}
__device__ __forceinline__ float bflo(unsigned x) { return __uint_as_float(x << 16); }
__device__ __forceinline__ float bfhi(unsigned x) { return __uint_as_float(x & 0xffff0000u); }

// ---------------- setup: fill (CSR buckets, 4B packed) + convert + Wc + bc ----------------
// slots entry: (src << 16) | w16  where w = w16 / 65535  (abs err <= 7.6e-6)
#define FILL_BLKS  2344   // 2344*256 >= EE
#define CONV_BLKS  6250   // 6250*256 float4 = NN*DD
__global__ void setup_kernel(const int* __restrict__ src, const int* __restrict__ dst,
                             const float* __restrict__ ea,
                             int* __restrict__ cnt, unsigned* __restrict__ slots,
                             const float* __restrict__ nodef, unsigned short* __restrict__ node_bf,
                             const float* __restrict__ W_rel, const float* __restrict__ W_root,
                             const float* __restrict__ W1, float* __restrict__ Wc,
                             const float* __restrict__ b_rel, const float* __restrict__ b1,
                             float* __restrict__ bc) {
    int b = blockIdx.x;
    if (b < FILL_BLKS) {                                 // edge fill
        int e = b * 256 + threadIdx.x;
        if (e >= EE) return;
        int d = dst[e];
        int p = atomicAdd(&cnt[d * CNTSTRIDE], 1);
        if (p < CAP) {
            unsigned w16 = (unsigned)__float2int_rn(ea[e] * 65535.0f);
            if (w16 > 65535u) w16 = 65535u;
            slots[d * CAP + p] = ((unsigned)src[e] << 16) | w16;
        }
    } else if (b < FILL_BLKS + CONV_BLKS) {              // node -> bf16
        int i = (b - FILL_BLKS) * 256 + threadIdx.x;
        float4 v = *(const float4*)&nodef[(size_t)i * 4];
        ushort4 o;
        o.x = f2bf(v.x); o.y = f2bf(v.y); o.z = f2bf(v.z); o.w = f2bf(v.w);
        *(ushort4*)&node_bf[(size_t)i * 4] = o;
    } else if (b < FILL_BLKS + CONV_BLKS + 96) {         // Wc: 6 products x 16 parts
        int bb = b - FILL_BLKS - CONV_BLKS;
        int which = bb >> 4, part = bb & 15;
        int l = (which < 3) ? which : which - 3;
        const float* A = (which < 3) ? (W_rel + (size_t)l * 16384) : (W_root + (size_t)l * 16384);
        const float* B = W1 + (size_t)l * 16384;
        float* out = Wc + (size_t)which * 16384;
        int o = part * 1024 + threadIdx.x;
        for (int rep = 0; rep < 4; ++rep, o += 256) {
            int i = o >> 7, j = o & 127;
            float s = 0.f;
            for (int k = 0; k < 128; ++k) s = fmaf(A[i * 128 + k], B[k * 128 + j], s);
            out[o] = s;
        }
    } else {                                             // bc: 3 blocks
        int l = b - FILL_BLKS - CONV_BLKS - 96;
        int j = threadIdx.x;
        if (j < 128) {
            float s = 0.f;
            for (int k = 0; k < 128; ++k)
                s = fmaf(b_rel[l * 128 + k], W1[(size_t)l * 16384 + k * 128 + j], s);
            bc[l * 128 + j] = s + b1[l * 128 + j];
        }
    }
}

// ---------------- pack weights into B-fragment-major bf16 ----------------
// 12 chunks: 0-2 Wc_rel[l], 3-5 Wc_root[l], 6-8 W2[l], 9-11 jk_W chunk l
__global__ void pack_w_kernel(const float* __restrict__ Wc, const float* __restrict__ W2,
                              const float* __restrict__ jkW, unsigned short* __restrict__ packed) {
    int t = blockIdx.x * 256 + threadIdx.x;   // 12*2048 threads
    int chunk = t >> 11;
    int r = t & 2047;
    int lane = r & 63;
    int tile = r >> 6;
    int kt = tile >> 3, nt = tile & 7;
    int quad = lane >> 4, n = lane & 15;
    const float* src;
    if (chunk < 6)       src = Wc  + (size_t)chunk * 16384;
    else if (chunk < 9)  src = W2  + (size_t)(chunk - 6) * 16384;
    else                 src = jkW + (size_t)(chunk - 9) * 16384;
    int k0 = kt * 32 + quad * 8;
    int col = nt * 16 + n;
    union { unsigned short u[8]; uint4 v; } tmp;
#pragma unroll
    for (int j = 0; j < 8; ++j) tmp.u[j] = f2bf(src[(size_t)(k0 + j) * DD + col]);
    *(uint4*)&packed[(size_t)t * 8] = tmp.v;
}

// ---------------- gather + mean: consecutive-edge groups, one slot load / 16 edges ----------------
// Wave = 1 node. Group g (16 lanes) owns edges j0+4g..j0+4g+3; lane covers 8 bf16 cols.
__global__ __launch_bounds__(256) void gather_mean_kernel(
    const unsigned short* __restrict__ feat,
    const unsigned* __restrict__ slots,
    const int* __restrict__ cnt,
    unsigned short* __restrict__ mean) {
    const int node = (int)((blockIdx.x * 256 + threadIdx.x) >> 6);
    if (node >= NN) return;
    const int lane = threadIdx.x & 63;
    const int g  = lane >> 4;         // edge group 0..3
    const int h8 = (lane & 15) * 8;   // first bf16 column handled by this lane
    int c = cnt[node * CNTSTRIDE];
    if (c > CAP) c = CAP;
    const unsigned* sp = slots + (size_t)node * CAP;

    float acc[8] = {0.f, 0.f, 0.f, 0.f, 0.f, 0.f, 0.f, 0.f};
    const float wscale = 1.0f / 65535.0f;

    for (int j0 = 0; j0 < c; j0 += 16) {
        // one broadcast 16B slot load covers this group's 4 edges
        uint4 sv = *(const uint4*)&sp[j0 + g * 4];
        unsigned se[4] = {sv.x, sv.y, sv.z, sv.w};
#pragma unroll
        for (int t = 0; t < 4; ++t) {
            int idx = j0 + g * 4 + t;
            bool ok = idx < c;
            unsigned e = se[t];
            int   srcn = ok ? (int)(e >> 16) : 0;           // clamp OOB (poisoned pad)
            float w    = ok ? (float)(e & 0xffffu) * wscale : 0.0f;
            uint4 v = *(const uint4*)&feat[(size_t)srcn * DD + h8];
            acc[0] = fmaf(bflo(v.x), w, acc[0]);
            acc[1] = fmaf(bfhi(v.x), w, acc[1]);
            acc[2] = fmaf(bflo(v.y), w, acc[2]);
            acc[3] = fmaf(bfhi(v.y), w, acc[3]);
            acc[4] = fmaf(bflo(v.z), w, acc[4]);
            acc[5] = fmaf(bfhi(v.z), w, acc[5]);
            acc[6] = fmaf(bflo(v.w), w, acc[6]);
            acc[7] = fmaf(bfhi(v.w), w, acc[7]);
        }
    }

    // reduce across the 4 edge-groups (lanes l, l^16, l^32, l^48 share columns)
#pragma unroll
    for (int k = 0; k < 8; ++k) {
        acc[k] += __shfl_xor(acc[k], 16);
        acc[k] += __shfl_xor(acc[k], 32);
    }

    if (g == 0) {
        float id = 1.0f / fmaxf((float)c, 1.0f);
        union { unsigned short u[8]; uint4 v; } o;
#pragma unroll
        for (int k = 0; k < 8; ++k) o.u[k] = f2bf(acc[k] * id);
        *(uint4*)&mean[(size_t)node * DD + h8] = o.v;
    }
}

// ---------------- barrier-free fused layer ----------------
// LN1ReLU(mean@Wc_rel + node@Wc_root + bc) @ W2 + b2 -> LN2ReLU [-> JK accumulate -> fp32 d_out]
template <bool JK>
__global__ __launch_bounds__(256) void fused_layer(
    const unsigned short* __restrict__ mean, const unsigned short* __restrict__ nodef,
    const unsigned short* __restrict__ PWrel, const unsigned short* __restrict__ PWroot,
    const unsigned short* __restrict__ PW2,
    const float* __restrict__ bc, const float* __restrict__ ln1g, const float* __restrict__ ln1b,
    const float* __restrict__ b2, const float* __restrict__ ln2g, const float* __restrict__ ln2b,
    unsigned short* __restrict__ out,
    const unsigned short* __restrict__ o0, const unsigned short* __restrict__ o1,
    const unsigned short* __restrict__ PJ0, const unsigned short* __restrict__ PJ1,
    const unsigned short* __restrict__ PJ2,
    const float* __restrict__ jkb, float* __restrict__ fout) {
    __shared__ unsigned short relay[4][16 * LDS_STRIDE];   // one tile per wave
    const int lane = threadIdx.x & 63;
    const int wid  = threadIdx.x >> 6;
    const int mrow = blockIdx.x * 64 + wid * 16;
    if (mrow >= NN) return;                                // barrier-free: safe

    const int quad = lane >> 4, n15 = lane & 15;
    const int kq   = quad * 8;
    unsigned short* wt = relay[wid];

    const unsigned short* Am = mean  + (size_t)(mrow + n15) * DD;
    const unsigned short* An = nodef + (size_t)(mrow + n15) * DD;

    f32x4 acc[8];
#pragma unroll
    for (int nt = 0; nt < 8; ++nt) acc[nt] = (f32x4){0.f, 0.f, 0.f, 0.f};
#pragma unroll
    for (int kt = 0; kt < 4; ++kt) {
        bf16x8 am = *(const bf16x8*)&Am[kt * 32 + kq];
        bf16x8 an = *(const bf16x8*)&An[kt * 32 + kq];
#pragma unroll
        for (int nt = 0; nt < 8; ++nt) {
            bf16x8 brel = *(const bf16x8*)&PWrel[(size_t)((kt * 8 + nt) * 64 + lane) * 8];
            acc[nt] = __builtin_amdgcn_mfma_f32_16x16x32_bf16(am, brel, acc[nt], 0, 0, 0);
            bf16x8 brt = *(const bf16x8*)&PWroot[(size_t)((kt * 8 + nt) * 64 + lane) * 8];
            acc[nt] = __builtin_amdgcn_mfma_f32_16x16x32_bf16(an, brt, acc[nt], 0, 0, 0);
        }
    }

    float x[8][4];
#pragma unroll
    for (int nt = 0; nt < 8; ++nt) {
        float bv = bc[nt * 16 + n15];
#pragma unroll
        for (int r = 0; r < 4; ++r) x[nt][r] = acc[nt][r] + bv;
    }
    {   // LN1 + ReLU
        float s[4] = {0, 0, 0, 0}, q[4] = {0, 0, 0, 0};
#pragma unroll
        for (int nt = 0; nt < 8; ++nt)
#pragma unroll
            for (int r = 0; r < 4; ++r) { s[r] += x[nt][r]; q[r] += x[nt][r] * x[nt][r]; }
#pragma unroll
        for (int m = 1; m <= 8; m <<= 1)
#pragma unroll
            for (int r = 0; r < 4; ++r) { s[r] += __shfl_xor(s[r], m); q[r] += __shfl_xor(q[r], m); }
        const float inv = 1.0f / 128.0f;
#pragma unroll
        for (int r = 0; r < 4; ++r) {
            float mu = s[r] * inv;
            float rs = rsqrtf(fmaxf(q[r] * inv - mu * mu, 0.0f) + 1e-5f);
#pragma unroll
            for (int nt = 0; nt < 8; ++nt) {
                float g = ln1g[nt * 16 + n15], bb = ln1b[nt * 16 + n15];
                x[nt][r] = fmaxf((x[nt][r] - mu) * rs * g + bb, 0.0f);
            }
        }
    }

#pragma unroll
    for (int nt = 0; nt < 8; ++nt)
#pragma unroll
        for (int r = 0; r < 4; ++r)
            wt[(quad * 4 + r) * LDS_STRIDE + nt * 16 + n15] = f2bf(x[nt][r]);
    __asm__ __volatile__("s_waitcnt lgkmcnt(0)" ::: "memory");

    f32x4 acc2[8];
#pragma unroll
    for (int nt = 0; nt < 8; ++nt) acc2[nt] = (f32x4){0.f, 0.f, 0.f, 0.f};
#pragma unroll
    for (int kt = 0; kt < 4; ++kt) {
        bf16x8 ah = *(const bf16x8*)&wt[n15 * LDS_STRIDE + kt * 32 + kq];
#pragma unroll
        for (int nt = 0; nt < 8; ++nt) {
            bf16x8 bw = *(const bf16x8*)&PW2[(size_t)((kt * 8 + nt) * 64 + lane) * 8];
            acc2[nt] = __builtin_amdgcn_mfma_f32_16x16x32_bf16(ah, bw, acc2[nt], 0, 0, 0);
        }
    }
#pragma unroll
    for (int nt = 0; nt < 8; ++nt) {
        float bv = b2[nt * 16 + n15];
#pragma unroll
        for (int r = 0; r < 4; ++r) x[nt][r] = acc2[nt][r] + bv;
    }
    {   // LN2 + ReLU
        float s[4] = {0, 0, 0, 0}, q[4] = {0, 0, 0, 0};
#pragma unroll
        for (int nt = 0; nt < 8; ++nt)
#pragma unroll
            for (int r = 0; r < 4; ++r) { s[r] += x[nt][r]; q[r] += x[nt][r] * x[nt][r]; }
#pragma unroll
        for (int m = 1; m <= 8; m <<= 1)
#pragma unroll
            for (int r = 0; r < 4; ++r) { s[r] += __shfl_xor(s[r], m); q[r] += __shfl_xor(q[r], m); }
        const float inv = 1.0f / 128.0f;
#pragma unroll
        for (int r = 0; r < 4; ++r) {
            float mu = s[r] * inv;
            float rs = rsqrtf(fmaxf(q[r] * inv - mu * mu, 0.0f) + 1e-5f);
#pragma unroll
            for (int nt = 0; nt < 8; ++nt) {
                float g = ln2g[nt * 16 + n15], bb = ln2b[nt * 16 + n15];
                x[nt][r] = fmaxf((x[nt][r] - mu) * rs * g + bb, 0.0f);
            }
        }
    }

    __asm__ __volatile__("s_waitcnt lgkmcnt(0)" ::: "memory");
#pragma unroll
    for (int nt = 0; nt < 8; ++nt)
#pragma unroll
        for (int r = 0; r < 4; ++r)
            wt[(quad * 4 + r) * LDS_STRIDE + nt * 16 + n15] = f2bf(x[nt][r]);
    __asm__ __volatile__("s_waitcnt lgkmcnt(0)" ::: "memory");

    if constexpr (!JK) {
#pragma unroll
        for (int i = 0; i < 4; ++i) {
            int s = i * 512 + lane * 8;
            int r = s >> 7, col = s & 127;
            uint4 v = *(const uint4*)&wt[r * LDS_STRIDE + col];
            *(uint4*)&out[(size_t)(mrow + r) * DD + col] = v;
        }
    } else {
        f32x4 accJ[8];
#pragma unroll
        for (int nt = 0; nt < 8; ++nt) accJ[nt] = (f32x4){0.f, 0.f, 0.f, 0.f};
#pragma unroll
        for (int kt = 0; kt < 4; ++kt) {
            bf16x8 ah = *(const bf16x8*)&wt[n15 * LDS_STRIDE + kt * 32 + kq];
#pragma unroll
            for (int nt = 0; nt < 8; ++nt) {
                bf16x8 bw = *(const bf16x8*)&PJ2[(size_t)((kt * 8 + nt) * 64 + lane) * 8];
                accJ[nt] = __builtin_amdgcn_mfma_f32_16x16x32_bf16(ah, bw, accJ[nt], 0, 0, 0);
            }
        }
        const unsigned short* A0 = o0 + (size_t)(mrow + n15) * DD;
        const unsigned short* A1 = o1 + (size_t)(mrow + n15) * DD;
#pragma unroll
        for (int kt = 0; kt < 4; ++kt) {
            bf16x8 a0 = *(const bf16x8*)&A0[kt * 32 + kq];
            bf16x8 a1 = *(const bf16x8*)&A1[kt * 32 + kq];
#pragma unroll
            for (int nt = 0; nt < 8; ++nt) {
                bf16x8 b0 = *(const bf16x8*)&PJ0[(size_t)((kt * 8 + nt) * 64 + lane) * 8];
                accJ[nt] = __builtin_amdgcn_mfma_f32_16x16x32_bf16(a0, b0, accJ[nt], 0, 0, 0);
                bf16x8 b1 = *(const bf16x8*)&PJ1[(size_t)((kt * 8 + nt) * 64 + lane) * 8];
                accJ[nt] = __builtin_amdgcn_mfma_f32_16x16x32_bf16(a1, b1, accJ[nt], 0, 0, 0);
            }
        }
#pragma unroll
        for (int nt = 0; nt < 8; ++nt) {
            float bv = jkb[nt * 16 + n15];
#pragma unroll
            for (int r = 0; r < 4; ++r)
                fout[(size_t)(mrow + quad * 4 + r) * DD + nt * 16 + n15] = accJ[nt][r] + bv;
        }
    }
}

// ---------------- launcher ----------------
extern "C" void kernel_launch(void* const* d_in, const int* in_sizes, int n_in,
                              void* d_out, int out_size, void* d_ws, size_t ws_size,
                              hipStream_t stream) {
    const float* node   = (const float*)d_in[0];
    const float* ea     = (const float*)d_in[1];
    const float* W_rel  = (const float*)d_in[2];
    const float* b_rel  = (const float*)d_in[3];
    const float* W_root = (const float*)d_in[4];
    const float* ln1_g  = (const float*)d_in[5];
    const float* ln1_b  = (const float*)d_in[6];
    const float* ln2_g  = (const float*)d_in[7];
    const float* ln2_b  = (const float*)d_in[8];
    const float* W1     = (const float*)d_in[9];
    const float* b1     = (const float*)d_in[10];
    const float* W2     = (const float*)d_in[11];
    const float* b2     = (const float*)d_in[12];
    const float* jk_W   = (const float*)d_in[13];
    const float* jk_b   = (const float*)d_in[14];
    const int*   ei     = (const int*)d_in[15];
    const int* srcI = ei;
    const int* dstI = ei + EE;

    char* ws = (char*)d_ws;
    size_t off = 0;
    auto alloc = [&](size_t bytes) {
        void* p = ws + off;
        off += (bytes + 255) & ~(size_t)255;
        return p;
    };
    int*            cnt     = (int*)alloc((size_t)NN * CNTSTRIDE * 4);
    unsigned*       slots   = (unsigned*)alloc((size_t)NN * CAP * 4);
    unsigned short* node_bf = (unsigned short*)alloc((size_t)NN * DD * 2);
    unsigned short* mean_bf = (unsigned short*)alloc((size_t)NN * DD * 2);
    unsigned short* outs_bf[2];
    for (int l = 0; l < 2; ++l) outs_bf[l] = (unsigned short*)alloc((size_t)NN * DD * 2);
    float*          Wc      = (float*)alloc((size_t)6 * 16384 * 4);
    float*          bc      = (float*)alloc((size_t)3 * 128 * 4);
    unsigned short* packed  = (unsigned short*)alloc((size_t)12 * 16384 * 2);

    hipMemsetAsync(cnt, 0, (size_t)NN * CNTSTRIDE * 4, stream);
    setup_kernel<<<FILL_BLKS + CONV_BLKS + 96 + 3, 256, 0, stream>>>(
        srcI, dstI, ea, cnt, slots, node, node_bf, W_rel, W_root, W1, Wc, b_rel, b1, bc);
    pack_w_kernel<<<12 * 2048 / 256, 256, 0, stream>>>(Wc, W2, jk_W, packed);

    const int gblocks = (NN + 63) / 64;   // 782
    unsigned short* cur = node_bf;
    for (int l = 0; l < 3; ++l) {
        gather_mean_kernel<<<NN / 4, 256, 0, stream>>>(cur, slots, cnt, mean_bf);
        if (l < 2) {
            fused_layer<false><<<gblocks, 256, 0, stream>>>(
                mean_bf, cur,
                packed + (size_t)l * 16384, packed + (size_t)(3 + l) * 16384,
                packed + (size_t)(6 + l) * 16384,
                bc + (size_t)l * DD, ln1_g + (size_t)l * DD, ln1_b + (size_t)l * DD,
                b2 + (size_t)l * DD, ln2_g + (size_t)l * DD, ln2_b + (size_t)l * DD,
                outs_bf[l],
                nullptr, nullptr, nullptr, nullptr, nullptr, nullptr, nullptr);
            cur = outs_bf[l];
        } else {
            fused_layer<true><<<gblocks, 256, 0, stream>>>(
                mean_bf, cur,
                packed + (size_t)l * 16384, packed + (size_t)(3 + l) * 16384,
                packed + (size_t)(6 + l) * 16384,
                bc + (size_t)l * DD, ln1_g + (size_t)l * DD, ln1_b + (size_t)l * DD,
                b2 + (size_t)l * DD, ln2_g + (size_t)l * DD, ln2_b + (size_t)l * DD,
                nullptr,
                outs_bf[0], outs_bf[1],
                packed + (size_t)9 * 16384, packed + (size_t)10 * 16384, packed + (size_t)11 * 16384,
                jk_b, (float*)d_out);
        }
    }
}